// Round 7
// baseline (65.631 us; speedup 1.0000x reference)
//
#include <hip/hip_runtime.h>
#include <hip/hip_bf16.h>
#include <stdint.h>

#define BATCH 8192
#define DIM   1024
#define BM 64
#define BN 64
#define BK 64
#define NT (DIM / BK)   // 16

typedef __attribute__((ext_vector_type(4))) float f32x4;
typedef __attribute__((ext_vector_type(8))) short bf16x8;
typedef __attribute__((ext_vector_type(4))) unsigned short u16x4;
typedef __attribute__((ext_vector_type(8))) unsigned short u16x8;

#define AS1(p) ((const __attribute__((address_space(1))) void*)(p))
#define AS3(p) ((__attribute__((address_space(3))) void*)(p))

__device__ __forceinline__ unsigned short f2bf(float f) {
    union { __hip_bfloat16 h; unsigned short u; } v;
    v.h = __hip_bfloat16(f);
    return v.u;
}

__device__ __forceinline__ float sigma_f(float x) {
    float x2 = x * x;
    return x2 * __builtin_amdgcn_rcpf(1.0f + x2);
}

// ---------------------------------------------------------------------------
// Kernel 1: convert A (f32 [D][D]) to bf16
// ---------------------------------------------------------------------------
__global__ __launch_bounds__(256) void convA_kernel(
    const float* __restrict__ A, unsigned short* __restrict__ Ab)
{
    int idx = blockIdx.x * 256 + threadIdx.x;
    f32x4 av = ((const f32x4*)A)[idx];
    u16x4 ab;
#pragma unroll
    for (int i = 0; i < 4; ++i) ab[i] = f2bf(av[i]);
    ((u16x4*)Ab)[idx] = ab;
}

// ---------------------------------------------------------------------------
// Kernel 2: fused, SMALL tiles for block-level TLP.
//   64x64 tile, 256 threads (4 waves, 2x2 grid, 32x32/wave, acc[2][2]).
//   LDS 32 KiB: dbuf 2 x {As 8K | Bs 8K}; epilogue C f32[64][64] reuses [0,16K).
//   5 blocks/CU resident (160 KiB LDS, 20 waves/CU); grid 2048 = 8 queued/CU.
//   Staggered blocks hide each other's barrier stalls (the R3-R6 defect).
// ---------------------------------------------------------------------------
__global__ __launch_bounds__(256, 5) void fused_kernel(
    const float* __restrict__ x, const float* __restrict__ ex,
    const float* __restrict__ W, const float* __restrict__ tgt,
    const unsigned short* __restrict__ Ab,
    float* __restrict__ out0, float* __restrict__ out1,
    float* __restrict__ out2)
{
    __shared__ __align__(16) char lds[32768];

    // ---- block mapping: 16 consecutive bms per XCD, bn fastest
    const int b     = blockIdx.x;
    const int xcd   = b & 7;
    const int local = b >> 3;                    // 0..255
    const int bm    = xcd * 16 + (local >> 4);   // 0..127
    const int bn    = local & 15;                // 0..15

    const int tid  = threadIdx.x;
    const int lane = tid & 63;
    const int wid  = tid >> 6;                   // 0..3
    const int wr   = wid >> 1;                   // 0..1
    const int wc   = wid & 1;                    // 0..1
    const int l15  = lane & 15;

    // ---- B staging (global_load_lds, pre-swizzled source, linear LDS dest)
    const int swz = (((lane & 7) ^ (lane >> 3)) << 4);
    const char* gBb = (const char*)Ab +
        ((size_t)(bn * BN + wid * 16 + (lane >> 3)) * DIM) * 2 + swz;

    // ---- A(sigma) staging: thread -> rows r0, r0+32; col group g (8 f32)
    const int r0 = tid >> 3;                     // 0..31
    const int g  = tid & 7;
    const float* gx = x + (size_t)(bm * BM + r0) * DIM + g * 8;
    const int wAoff = (g * 16) ^ ((r0 & 7) << 4);

    // ---- fragment read constants
    const int rd_sw = (lane & 7) << 4;
    const int cb0   = (lane >> 4) << 4;

    f32x4 acc[2][2];
#pragma unroll
    for (int mi = 0; mi < 2; ++mi)
#pragma unroll
        for (int ni = 0; ni < 2; ++ni)
            acc[mi][ni] = f32x4{0.f, 0.f, 0.f, 0.f};

    auto stageB = [&](int k, char* Bs) {
#pragma unroll
        for (int j = 0; j < 2; ++j)
            __builtin_amdgcn_global_load_lds(
                AS1(gBb + (size_t)j * (8 * DIM * 2) + (size_t)k * 2),
                AS3(Bs + (wid * 16 + j * 8) * 128), 16, 0, 0);
    };
    auto loadX = [&](int k, f32x4 xa[2][2]) {
#pragma unroll
        for (int s = 0; s < 2; ++s) {
            xa[s][0] = *(const f32x4*)(gx + (size_t)s * 32 * DIM + k);
            xa[s][1] = *(const f32x4*)(gx + (size_t)s * 32 * DIM + k + 4);
        }
    };
    auto writeSig = [&](char* As, f32x4 xa[2][2]) {
#pragma unroll
        for (int s = 0; s < 2; ++s) {
            u16x8 sb;
#pragma unroll
            for (int i = 0; i < 4; ++i) {
                sb[i]     = f2bf(sigma_f(xa[s][0][i]));
                sb[i + 4] = f2bf(sigma_f(xa[s][1][i]));
            }
            *(u16x8*)(As + (r0 + s * 32) * 128 + wAoff) = sb;
        }
    };

    // ---------------- prologue: stage tile 0 into buffer 0
    {
        f32x4 xa[2][2];
        loadX(0, xa);
        stageB(0, lds + 8192);
        writeSig(lds, xa);
    }
    __syncthreads();

    // ---------------- main K loop
    for (int t = 0; t < NT; ++t) {
        const int cur = t & 1;
        f32x4 xa[2][2];
        if (t + 1 < NT) {
            loadX((t + 1) * BK, xa);
            stageB((t + 1) * BK, lds + (cur ^ 1) * 16384 + 8192);
        }
        __builtin_amdgcn_sched_barrier(0);

        const char* As_ = lds + cur * 16384;
        const char* Bs_ = As_ + 8192;
#pragma unroll
        for (int kk = 0; kk < 2; ++kk) {
            bf16x8 af[2], bfr[2];
#pragma unroll
            for (int mi = 0; mi < 2; ++mi)
                af[mi] = *(const bf16x8*)(As_ + (wr * 32 + mi * 16 + l15) * 128 +
                                          ((cb0 + kk * 64) ^ rd_sw));
#pragma unroll
            for (int ni = 0; ni < 2; ++ni)
                bfr[ni] = *(const bf16x8*)(Bs_ + (wc * 32 + ni * 16 + l15) * 128 +
                                           ((cb0 + kk * 64) ^ rd_sw));
#pragma unroll
            for (int mi = 0; mi < 2; ++mi)
#pragma unroll
                for (int ni = 0; ni < 2; ++ni)
                    acc[mi][ni] = __builtin_amdgcn_mfma_f32_16x16x32_bf16(
                        af[mi], bfr[ni], acc[mi][ni], 0, 0, 0);
        }
        __builtin_amdgcn_sched_barrier(0);

        if (t + 1 < NT) writeSig(lds + (cur ^ 1) * 16384, xa);
        __syncthreads();
    }

    // ---------------- epilogue: acc -> LDS C f32[64][64] (linear)
#pragma unroll
    for (int mi = 0; mi < 2; ++mi)
#pragma unroll
        for (int ni = 0; ni < 2; ++ni) {
            const int row_ = wr * 32 + mi * 16 + ((lane >> 4) << 2);
            const int colb = (wc * 32 + ni * 16 + l15) * 4;
#pragma unroll
            for (int r = 0; r < 4; ++r)
                *(float*)(lds + (row_ + r) * 256 + colb) = acc[mi][ni][r];
        }
    __syncthreads();

    // ---- streaming pass: row-major, fully vectorized (4 v4 per thread)
#pragma unroll
    for (int p = 0; p < 4; ++p) {
        const int ci  = tid + p * 256;
        const int row = ci >> 4;                 // 0..63
        const int cv  = ci & 15;                 // f32x4 col index
        f32x4 c = *(const f32x4*)(lds + row * 256 + cv * 16);
        const size_t v4 = (size_t)(bm * BM + row) * (DIM / 4) + bn * (BN / 4) + cv;
        f32x4 xv = ((const f32x4*)x)[v4];
        f32x4 ev = ((const f32x4*)ex)[v4];
        f32x4 wv = ((const f32x4*)W)[v4];
        f32x4 tv = ((const f32x4*)tgt)[bn * (BN / 4) + cv];
        f32x4 o0;
#pragma unroll
        for (int e = 0; e < 4; ++e) {
            float xi = xv[e], ti = tv[e];
            float ba = ti * ti * __builtin_amdgcn_rcpf(1.0f + ti * ti);
            float u  = -(wv[e] * (xi + ev[e] - ti)) * ba;
            float s  = sigma_f(xi);
            o0[e] = -xi + u * s + c[e];
        }
        ((f32x4*)out0)[v4] = o0;
        ((f32x4*)out1)[v4] = -o0;
        ((f32x4*)out2)[v4] = f32x4{0.f, 0.f, 0.f, 0.f};
    }
}

// ---------------------------------------------------------------------------
extern "C" void kernel_launch(void* const* d_in, const int* in_sizes, int n_in,
                              void* d_out, int out_size, void* d_ws, size_t ws_size,
                              hipStream_t stream)
{
    const float* x   = (const float*)d_in[0];
    const float* ex  = (const float*)d_in[1];
    const float* W   = (const float*)d_in[2];
    const float* A   = (const float*)d_in[3];
    const float* tgt = (const float*)d_in[4];

    float* out0 = (float*)d_out;
    float* out1 = out0 + (size_t)BATCH * DIM;
    float* out2 = out1 + (size_t)BATCH * DIM;

    unsigned short* Abf = (unsigned short*)d_ws;   // 2 MiB

    convA_kernel<<<DIM * DIM / 4 / 256, 256, 0, stream>>>(A, Abf);
    fused_kernel<<<(BATCH / BM) * (DIM / BN), 256, 0, stream>>>(
        x, ex, W, tgt, Abf, out0, out1, out2);
}